// Round 6
// baseline (146.020 us; speedup 1.0000x reference)
//
#include <hip/hip_runtime.h>
#include <math.h>

// DynamicElementAggregator: B=2, N=1024, M=1024, D=768, F=384, H=72
#define B_ 2
#define N_ 1024
#define M_ 1024
#define D_ 768
#define F_ 384
#define H_ 72
#define ROWS 8   // rows per block

typedef float f32x4 __attribute__((ext_vector_type(4)));

// ---- Fully fused: rw = GELU(x@W1+b1)@W2+b2 (in LDS), then
//      out[b,n,:] = sum_h rw[n,h] * scores[b,h,n,:] + bias
// 256 blocks x 512 threads, 8 rows/block, 1 block/CU.
// MLP phase ~9-10 us (L2-bound on W1 re-read, 1.18 MB/block);
// combine phase streams 604 MB of scores in 32 KB contiguous spans per head.
__global__ __launch_bounds__(512) void fused_kernel(
    const float* __restrict__ x, const float* __restrict__ scores,
    const float* __restrict__ W1, const float* __restrict__ b1,
    const float* __restrict__ W2, const float* __restrict__ b2,
    const float* __restrict__ bias, float* __restrict__ out)
{
    const int t = threadIdx.x;            // 0..511
    const int blk = blockIdx.x;           // 0..255
    const int b = blk >> 7;
    const int n0 = (blk & 127) * ROWS;
    const int row0 = (b << 10) + n0;      // global flattened row

    __shared__ float xs[ROWS][D_];        // 24 KB
    __shared__ float hs[ROWS][F_ + 8];    // 12.25 KB (pitch 392, 16B-aligned)
    __shared__ float rw[ROWS][80];        // 2.5 KB

    // ---- stage x rows (coalesced float4: 1536 = 3*512) ----
    {
        const f32x4* xg = reinterpret_cast<const f32x4*>(x + row0 * D_);
        f32x4* xl = reinterpret_cast<f32x4*>(&xs[0][0]);
#pragma unroll
        for (int i = 0; i < 3; ++i)
            xl[t + i * 512] = xg[t + i * 512];
    }
    __syncthreads();

    // ---- layer 1: thread f (<384) owns hidden col f for all 8 rows ----
    if (t < F_) {
        const int f = t;
        float acc[ROWS];
#pragma unroll
        for (int r = 0; r < ROWS; ++r) acc[r] = 0.0f;

#pragma unroll 4
        for (int d = 0; d < D_; d += 4) {   // 16 W1 loads in flight at unroll 4
            const float w0 = W1[(d + 0) * F_ + f];
            const float w1v = W1[(d + 1) * F_ + f];
            const float w2v = W1[(d + 2) * F_ + f];
            const float w3v = W1[(d + 3) * F_ + f];
#pragma unroll
            for (int r = 0; r < ROWS; ++r) {
                const float4 xv = *reinterpret_cast<const float4*>(&xs[r][d]);
                acc[r] = fmaf(xv.x, w0, acc[r]);
                acc[r] = fmaf(xv.y, w1v, acc[r]);
                acc[r] = fmaf(xv.z, w2v, acc[r]);
                acc[r] = fmaf(xv.w, w3v, acc[r]);
            }
        }
        const float bb = b1[f];
#pragma unroll
        for (int r = 0; r < ROWS; ++r) {
            const float v = acc[r] + bb;
            hs[r][f] = 0.5f * v * (1.0f + erff(v * 0.70710678118654752f));
        }
    }
    __syncthreads();

    // ---- layer 2: 576 outputs (8 rows x 72 heads) -> rw in LDS ----
#pragma unroll 1
    for (int o = t; o < ROWS * H_; o += 512) {
        const int r = o / H_;
        const int c = o - r * H_;           // consecutive lanes -> consecutive c
        float s = 0.0f;
#pragma unroll 4
        for (int k = 0; k < F_; k += 4) {
            const float4 hv = *reinterpret_cast<const float4*>(&hs[r][k]);
            s = fmaf(hv.x, W2[(k + 0) * H_ + c], s);
            s = fmaf(hv.y, W2[(k + 1) * H_ + c], s);
            s = fmaf(hv.z, W2[(k + 2) * H_ + c], s);
            s = fmaf(hv.w, W2[(k + 3) * H_ + c], s);
        }
        rw[r][c] = s + b2[c];
    }
    __syncthreads();

    // ---- combine: thread (rp, col) owns rows rp*4..rp*4+3 at float4 col ----
    const int col = t & 255;
    const int rp = t >> 8;                  // 0 or 1
    const int r0 = rp * 4;

    const f32x4* __restrict__ sp = reinterpret_cast<const f32x4*>(scores);
    const int base = ((b * H_) * N_ + (n0 + r0)) * (M_ / 4) + col;
    const int hstr = N_ * (M_ / 4);         // 262144 float4 per head

    f32x4 a0 = 0.f, a1 = 0.f, a2 = 0.f, a3 = 0.f;
#pragma unroll 2
    for (int h = 0; h < H_; ++h) {
        const int ib = base + h * hstr;
        const f32x4 v0 = __builtin_nontemporal_load(sp + ib);
        const f32x4 v1 = __builtin_nontemporal_load(sp + ib + 256);
        const f32x4 v2 = __builtin_nontemporal_load(sp + ib + 512);
        const f32x4 v3 = __builtin_nontemporal_load(sp + ib + 768);
        const float w0 = rw[r0 + 0][h];
        const float w1 = rw[r0 + 1][h];
        const float w2 = rw[r0 + 2][h];
        const float w3 = rw[r0 + 3][h];
#pragma unroll
        for (int j = 0; j < 4; ++j) {
            a0[j] = fmaf(w0, v0[j], a0[j]);
            a1[j] = fmaf(w1, v1[j], a1[j]);
            a2[j] = fmaf(w2, v2[j], a2[j]);
            a3[j] = fmaf(w3, v3[j], a3[j]);
        }
    }

    const float bv = bias[0];
#pragma unroll
    for (int j = 0; j < 4; ++j) { a0[j] += bv; a1[j] += bv; a2[j] += bv; a3[j] += bv; }

    f32x4* __restrict__ op = reinterpret_cast<f32x4*>(out);
    const int obase = (row0 + r0) * (M_ / 4) + col;
    __builtin_nontemporal_store(a0, op + obase);
    __builtin_nontemporal_store(a1, op + obase + 256);
    __builtin_nontemporal_store(a2, op + obase + 512);
    __builtin_nontemporal_store(a3, op + obase + 768);
}

extern "C" void kernel_launch(void* const* d_in, const int* in_sizes, int n_in,
                              void* d_out, int out_size, void* d_ws, size_t ws_size,
                              hipStream_t stream) {
    const float* x      = (const float*)d_in[0];
    const float* scores = (const float*)d_in[1];
    const float* W1     = (const float*)d_in[2];
    const float* b1     = (const float*)d_in[3];
    const float* W2     = (const float*)d_in[4];
    const float* b2     = (const float*)d_in[5];
    const float* bias   = (const float*)d_in[6];
    float* out = (float*)d_out;

    fused_kernel<<<(B_ * N_) / ROWS, 512, 0, stream>>>(
        x, scores, W1, b1, W2, b2, bias, out);
}